// Round 3
// baseline (285.749 us; speedup 1.0000x reference)
//
#include <hip/hip_runtime.h>
#include <stdint.h>

// Problem dims (fixed by reference setup_inputs):
//   x: (64, 65536, 10) f32, integer labels 0..9
//   B=64, C=10, D=65536, K=8, NJ=D/K=8192
//   window (b,c,j) = in[(b*C+c)*D + j*8 .. +8)
//   out[c*NJ*B + j*B + b] = mode(window), ties -> smallest value
//
// ROUND 3 = DIAGNOSTIC: kernel launched 3x (idempotent) to expose t_kernel
// via dur_us delta, since harness fills crowd out the rocprof top-5.
#define BB 64
#define CC 10
#define DD 65536
#define KK 8
#define NJ 8192          // DD / KK
#define JT 64            // j-tile per block
#define NBLK_J (NJ / JT) // 128

__global__ __launch_bounds__(256) void mode_pool_kernel(const float* __restrict__ in,
                                                        float* __restrict__ out) {
    const int c  = blockIdx.x >> 7;
    const int j0 = (blockIdx.x & (NBLK_J - 1)) * JT;
    const int tid  = threadIdx.x;
    const int lane = tid & 63;   // == (tid + m*256) & 63 for any m

    // lds[j_local][b], padded row stride 65 -> 2-way bank aliasing only (free)
    __shared__ float lds[JT * 65];

    // Phase 1: 4096 windows per block, 16 per thread, grouped 4-at-a-time so
    // 8 dwordx4 loads are in flight before the dependent compute (MLP).
    #pragma unroll
    for (int g = 0; g < 4; ++g) {
        float4 lo[4], hi[4];
        #pragma unroll
        for (int t = 0; t < 4; ++t) {
            const int i = tid + (g * 4 + t) * 256;
            const int b = i >> 6;  // 0..63
            const size_t base = ((size_t)(b * CC + c)) * DD + (size_t)(j0 + lane) * KK;
            lo[t] = *(const float4*)(in + base);
            hi[t] = *(const float4*)(in + base + 4);
        }
        #pragma unroll
        for (int t = 0; t < 4; ++t) {
            const int i = tid + (g * 4 + t) * 256;
            const int b = i >> 6;
            const float v[8] = {lo[t].x, lo[t].y, lo[t].z, lo[t].w,
                                hi[t].x, hi[t].y, hi[t].z, hi[t].w};
            // Nibble histogram: labels 0..9 -> bins at bit 4*v; counts <= 8 fit
            // a nibble, no cross-nibble carries possible.
            uint64_t histo = 0;
            #pragma unroll
            for (int a = 0; a < 8; ++a) {
                histo += 1ull << (((int)v[a]) << 2);
            }
            // Ascending scan, strict '>' keeps the smallest modal value on ties.
            int bc = 0, bv = 0;
            #pragma unroll
            for (int val = 0; val < 10; ++val) {
                const int cnt = (int)((histo >> (val * 4)) & 15u);
                const bool better = cnt > bc;
                bc = better ? cnt : bc;
                bv = better ? val : bv;
            }
            lds[lane * 65 + b] = (float)bv;
        }
    }

    __syncthreads();

    // Phase 2: contiguous float4 stores of the 4096-float tile.
    // out chunk base = c*NJ*B + j0*B, layout within chunk: pos = j_local*64 + b.
    float4* outv = (float4*)(out + (size_t)c * NJ * BB + (size_t)j0 * BB);
    #pragma unroll
    for (int k = 0; k < 4; ++k) {
        const int v4 = tid + k * 256;        // 0..1023
        const int row = v4 >> 4;             // j_local
        const int col = (v4 & 15) * 4;       // b base
        const float* p = &lds[row * 65 + col];
        float4 o;
        o.x = p[0]; o.y = p[1]; o.z = p[2]; o.w = p[3];
        outv[v4] = o;
    }
}

extern "C" void kernel_launch(void* const* d_in, const int* in_sizes, int n_in,
                              void* d_out, int out_size, void* d_ws, size_t ws_size,
                              hipStream_t stream) {
    const float* in = (const float*)d_in[0];
    float* out = (float*)d_out;
    dim3 grid(CC * NBLK_J);  // 1280 blocks
    dim3 block(256);
    // DIAGNOSTIC: 3 identical idempotent launches. t_kernel = (dur - 233.7)/2.
    mode_pool_kernel<<<grid, block, 0, stream>>>(in, out);
    mode_pool_kernel<<<grid, block, 0, stream>>>(in, out);
    mode_pool_kernel<<<grid, block, 0, stream>>>(in, out);
}

// Round 4
// 232.407 us; speedup vs baseline: 1.2295x; 1.2295x over previous
//
#include <hip/hip_runtime.h>
#include <stdint.h>

// Problem dims (fixed by reference setup_inputs):
//   x: (64, 65536, 10) f32, integer labels 0..9
//   B=64, C=10, D=65536, K=8, NJ=D/K=8192
//   window (b,c,j) = in[(b*C+c)*D + j*8 .. +8)
//   out[c*NJ*B + j*B + b] = mode(window), ties -> smallest value
//
// Measured (R3 diagnostic, 3x-launch delta): t_kernel ~= 26 us for 188.8 MB
// compulsory traffic = 7.3 TB/s effective (above 6.3 TB/s HBM achievable;
// reads are L3-resident after the harness's d_in restore). Memory roofline.
#define BB 64
#define CC 10
#define DD 65536
#define KK 8
#define NJ 8192          // DD / KK
#define JT 64            // j-tile per block
#define NBLK_J (NJ / JT) // 128

__global__ __launch_bounds__(256) void mode_pool_kernel(const float* __restrict__ in,
                                                        float* __restrict__ out) {
    const int c  = blockIdx.x >> 7;
    const int j0 = (blockIdx.x & (NBLK_J - 1)) * JT;
    const int tid  = threadIdx.x;
    const int lane = tid & 63;   // == (tid + m*256) & 63 for any m

    // lds[j_local][b], padded row stride 65 -> 2-way bank aliasing only (free)
    __shared__ float lds[JT * 65];

    // Phase 1: 4096 windows per block, 16 per thread, grouped 4-at-a-time so
    // 8 dwordx4 loads are in flight before the dependent compute (MLP).
    #pragma unroll
    for (int g = 0; g < 4; ++g) {
        float4 lo[4], hi[4];
        #pragma unroll
        for (int t = 0; t < 4; ++t) {
            const int i = tid + (g * 4 + t) * 256;
            const int b = i >> 6;  // 0..63
            const size_t base = ((size_t)(b * CC + c)) * DD + (size_t)(j0 + lane) * KK;
            lo[t] = *(const float4*)(in + base);
            hi[t] = *(const float4*)(in + base + 4);
        }
        #pragma unroll
        for (int t = 0; t < 4; ++t) {
            const int i = tid + (g * 4 + t) * 256;
            const int b = i >> 6;
            const float v[8] = {lo[t].x, lo[t].y, lo[t].z, lo[t].w,
                                hi[t].x, hi[t].y, hi[t].z, hi[t].w};
            // Nibble histogram: labels 0..9 -> bins at bit 4*v; counts <= 8 fit
            // a nibble, no cross-nibble carries possible.
            uint64_t histo = 0;
            #pragma unroll
            for (int a = 0; a < 8; ++a) {
                histo += 1ull << (((int)v[a]) << 2);
            }
            // Ascending scan, strict '>' keeps the smallest modal value on ties.
            int bc = 0, bv = 0;
            #pragma unroll
            for (int val = 0; val < 10; ++val) {
                const int cnt = (int)((histo >> (val * 4)) & 15u);
                const bool better = cnt > bc;
                bc = better ? cnt : bc;
                bv = better ? val : bv;
            }
            lds[lane * 65 + b] = (float)bv;
        }
    }

    __syncthreads();

    // Phase 2: contiguous float4 stores of the 4096-float tile.
    // out chunk base = c*NJ*B + j0*B, layout within chunk: pos = j_local*64 + b.
    float4* outv = (float4*)(out + (size_t)c * NJ * BB + (size_t)j0 * BB);
    #pragma unroll
    for (int k = 0; k < 4; ++k) {
        const int v4 = tid + k * 256;        // 0..1023
        const int row = v4 >> 4;             // j_local
        const int col = (v4 & 15) * 4;       // b base
        const float* p = &lds[row * 65 + col];
        float4 o;
        o.x = p[0]; o.y = p[1]; o.z = p[2]; o.w = p[3];
        outv[v4] = o;
    }
}

extern "C" void kernel_launch(void* const* d_in, const int* in_sizes, int n_in,
                              void* d_out, int out_size, void* d_ws, size_t ws_size,
                              hipStream_t stream) {
    const float* in = (const float*)d_in[0];
    float* out = (float*)d_out;
    dim3 grid(CC * NBLK_J);  // 1280 blocks
    dim3 block(256);
    mode_pool_kernel<<<grid, block, 0, stream>>>(in, out);
}